// Round 7
// baseline (7577.778 us; speedup 1.0000x reference)
//
#include <hip/hip_runtime.h>
#include <hip/hip_bf16.h>
#include <math.h>

#define V 32000
#define E 512
#define H 1024
#define SQ 128
#define T 100
#define NB 256      // k_a blocks
#define NTI 256
#define NTA 512
#define NBB 500     // k_b blocks (FC): 500 x 64 rows = 32000
#define BROWS 64    // fc rows per k_b block
#define NTB 256     // k_b threads (4 waves -> 2 blocks/CU)
#define NTC 1024    // k_c threads (single block)
#define NP 512      // partials array size (k_b writes 500, rest identity-padded)
#define GROWS 16    // 4096 gate rows / 256 k_a blocks
#define FROWS 125   // 32000 logp rows / 256 k_a blocks
#define NEG_BIG (-1e30f)

typedef unsigned int u32;
typedef unsigned long long u64;

struct WS {
  float gates[4*H];        // gate pre-activations for current step
  float h[H];              // hidden state (written by k_c)
  float c[2][H];           // cell state, double-buffered by step parity
  float concat[2*H];       // [0,H) = h2, [H,2H) = ctx (written by k_c)
  float logits[V];         // raw logits of current step
  float pmax[NP];          // per-k_b-block max logit
  float psum[NP];          // per-k_b-block sum exp(logit - blockmax)
  u64   pkey[NP];          // per-k_b-block packed argmax key
};

__device__ __forceinline__ float wave_sum(float v){
  #pragma unroll
  for (int m = 32; m; m >>= 1) v += __shfl_xor(v, m, 64);
  return v;
}

__device__ __forceinline__ float wave_max(float v){
  #pragma unroll
  for (int m = 32; m; m >>= 1) v = fmaxf(v, __shfl_xor(v, m, 64));
  return v;
}

__device__ __forceinline__ u64 wave_max_u64(u64 v){
  #pragma unroll
  for (int m = 32; m; m >>= 1){
    u64 o = __shfl_xor(v, m, 64);
    v = (o > v) ? o : v;
  }
  return v;
}

__device__ __forceinline__ float dot4(float4 w, const float* v){
  return w.x*v[0] + w.y*v[1] + w.z*v[2] + w.w*v[3];
}

__global__ void __launch_bounds__(NTI) k_init(const float* __restrict__ hn,
                                              const float* __restrict__ cn,
                                              WS* __restrict__ ws){
  int tid = threadIdx.x;
  for (int j = tid; j < H; j += NTI){
    ws->h[j]    = hn[j];
    ws->c[0][j] = cn[j];
  }
  for (int i = tid; i < NP; i += NTI){
    ws->pmax[i] = NEG_BIG;
    ws->psum[i] = 0.f;
    ws->pkey[i] = 0ull;
  }
}

// k_a(t): finalize step t-1 (logZ, logp writes, index, token decode), then gates for step t
__global__ void __launch_bounds__(NTA) k_a(const float* __restrict__ emb,
                                           const float* __restrict__ W_ih,
                                           const float* __restrict__ W_hh,
                                           const float* __restrict__ b_ih,
                                           const float* __restrict__ b_hh,
                                           WS* __restrict__ ws,
                                           float* __restrict__ out,
                                           int t){
  __shared__ float bc_logZ;
  __shared__ int   bc_tok;
  int b = blockIdx.x, tid = threadIdx.x;
  int wv = tid >> 6, ln = tid & 63;
  int tok = 2;  // SOS

  if (t > 0){
    // wave 0 reduces the 512 (identity-padded) per-block partials via shuffles
    if (wv == 0){
      float mb[8], sb[8]; u64 kb[8];
      #pragma unroll
      for (int k = 0; k < 8; ++k){
        mb[k] = ws->pmax[ln + k*64];
        sb[k] = ws->psum[ln + k*64];
        kb[k] = ws->pkey[ln + k*64];
      }
      float mx = mb[0];
      #pragma unroll
      for (int k = 1; k < 8; ++k) mx = fmaxf(mx, mb[k]);
      float m = wave_max(mx);
      float S = 0.f;
      #pragma unroll
      for (int k = 0; k < 8; ++k) S += sb[k] * expf(mb[k] - m);  // padded: 0*exp(-inf)=0
      S = wave_sum(S);
      u64 key = kb[0];
      #pragma unroll
      for (int k = 1; k < 8; ++k) key = (kb[k] > key) ? kb[k] : key;
      key = wave_max_u64(key);
      if (ln == 0){
        bc_logZ = m + logf(fmaxf(S, 1e-30f));
        int tk = (int)(~(u32)key);
        if ((u32)tk >= (u32)V) tk = 2;    // defensive
        bc_tok = tk;
      }
    }
    __syncthreads();
    float logZ = bc_logZ;
    tok = bc_tok;

    if (tid < FROWS){
      int row = b*FROWS + tid;
      // nt store: logp output is never re-read — don't pollute caches
      __builtin_nontemporal_store(ws->logits[row] - logZ,
                                  &out[(size_t)(t-1)*V + row]);
    }
    if (b == 0 && tid == 0)
      out[(size_t)T*V + (t-1)] = (float)tok;   // indices chunk, stored as f32
  }

  if (t < T){
    // preload lane slices of x = emb[tok] (8 elems) and h (16 elems), reused across rows
    float xv[8], hv[16];
    {
      const float4* xp = (const float4*)(emb + (size_t)tok*E) + ln*2;
      float4 x0 = xp[0], x1 = xp[1];
      xv[0]=x0.x; xv[1]=x0.y; xv[2]=x0.z; xv[3]=x0.w;
      xv[4]=x1.x; xv[5]=x1.y; xv[6]=x1.z; xv[7]=x1.w;
      const float4* hp = (const float4*)(ws->h) + ln*4;
      float4 h0 = hp[0], h1 = hp[1], h2 = hp[2], h3 = hp[3];
      hv[0]=h0.x; hv[1]=h0.y; hv[2]=h0.z; hv[3]=h0.w;
      hv[4]=h1.x; hv[5]=h1.y; hv[6]=h1.z; hv[7]=h1.w;
      hv[8]=h2.x; hv[9]=h2.y; hv[10]=h2.z; hv[11]=h2.w;
      hv[12]=h3.x; hv[13]=h3.y; hv[14]=h3.z; hv[15]=h3.w;
    }
    // 8 waves, each handles a PAIR of the block's 16 gate rows; all 12 row-loads
    // issued back-to-back so they stay in flight together (MLP).
    int rl0 = wv*2;
    int row0 = b*GROWS + rl0, row1 = row0 + 1;
    const float4* ap0 = (const float4*)(W_ih + (size_t)row0*E) + ln*2;
    const float4* ap1 = (const float4*)(W_ih + (size_t)row1*E) + ln*2;
    const float4* wh0 = (const float4*)(W_hh + (size_t)row0*H) + ln*4;
    const float4* wh1 = (const float4*)(W_hh + (size_t)row1*H) + ln*4;
    float4 ia[2], ib[2], ha[4], hb[4];
    #pragma unroll
    for (int k = 0; k < 2; ++k) ia[k] = ap0[k];
    #pragma unroll
    for (int k = 0; k < 2; ++k) ib[k] = ap1[k];
    #pragma unroll
    for (int k = 0; k < 4; ++k) ha[k] = wh0[k];
    #pragma unroll
    for (int k = 0; k < 4; ++k) hb[k] = wh1[k];
    float acc0 = dot4(ia[0], xv) + dot4(ia[1], xv+4)
               + dot4(ha[0], hv) + dot4(ha[1], hv+4) + dot4(ha[2], hv+8) + dot4(ha[3], hv+12);
    float acc1 = dot4(ib[0], xv) + dot4(ib[1], xv+4)
               + dot4(hb[0], hv) + dot4(hb[1], hv+4) + dot4(hb[2], hv+8) + dot4(hb[3], hv+12);
    acc0 = wave_sum(acc0);
    acc1 = wave_sum(acc1);
    if (ln == 0){
      ws->gates[row0] = acc0 + b_ih[row0] + b_hh[row0];
      ws->gates[row1] = acc1 + b_ih[row1] + b_hh[row1];
    }
  }
}

// k_c(t): single block. cell -> h2, attention scores, softmax, ctx.
// Replaces the per-block redundant phases 1-4 of the old k_b (256x less traffic).
__global__ void __launch_bounds__(NTC) k_c(const float* __restrict__ enc,
                                           WS* __restrict__ ws,
                                           int t){
  __shared__ float h2s[H];
  __shared__ float sc[SQ];
  __shared__ float pw[SQ];
  int tid = threadIdx.x;
  int wv = tid >> 6, ln = tid & 63;   // 16 waves

  // phase 1: LSTM cell update (1 element per thread); persist h,c and h2
  {
    int j = tid;
    float gi = ws->gates[j];
    float gf = ws->gates[H + j];
    float gg = ws->gates[2*H + j];
    float go = ws->gates[3*H + j];
    float co = ws->c[t & 1][j];
    float si = 1.f/(1.f + expf(-gi));
    float sf = 1.f/(1.f + expf(-gf));
    float tg = tanhf(gg);
    float so = 1.f/(1.f + expf(-go));
    float cn = sf*co + si*tg;
    float hn = so*tanhf(cn);
    ws->c[(t+1) & 1][j] = cn;
    ws->h[j] = hn;
    ws->concat[j] = hn;
    h2s[j] = hn;
  }
  __syncthreads();

  // phase 2: scores = enc @ h2 (16 waves x 8 rows, paired for MLP)
  {
    float hv[16];
    #pragma unroll
    for (int k = 0; k < 16; ++k) hv[k] = h2s[ln*16 + k];
    #pragma unroll
    for (int u = 0; u < 4; ++u){
      int s0 = wv*8 + u*2, s1 = s0 + 1;
      const float4* e0p = (const float4*)(enc + (size_t)s0*H) + ln*4;
      const float4* e1p = (const float4*)(enc + (size_t)s1*H) + ln*4;
      float4 e0[4], e1[4];
      #pragma unroll
      for (int k = 0; k < 4; ++k) e0[k] = e0p[k];
      #pragma unroll
      for (int k = 0; k < 4; ++k) e1[k] = e1p[k];
      float acc0 = dot4(e0[0], hv) + dot4(e0[1], hv+4) + dot4(e0[2], hv+8) + dot4(e0[3], hv+12);
      float acc1 = dot4(e1[0], hv) + dot4(e1[1], hv+4) + dot4(e1[2], hv+8) + dot4(e1[3], hv+12);
      acc0 = wave_sum(acc0);
      acc1 = wave_sum(acc1);
      if (ln == 0){ sc[s0] = acc0; sc[s1] = acc1; }
    }
  }
  __syncthreads();

  // phase 3: softmax over 128 scores — wave 0 only, shuffle reduce
  if (wv == 0){
    float v0 = sc[ln], v1 = sc[ln + 64];
    float m = wave_max(fmaxf(v0, v1));
    float e0 = expf(v0 - m), e1 = expf(v1 - m);
    float S = wave_sum(e0 + e1);
    pw[ln]      = e0 / S;
    pw[ln + 64] = e1 / S;
  }
  __syncthreads();

  // phase 4: ctx[col] = sum_s pw[s] * enc[s][col]; one col per thread (coalesced)
  {
    int col = tid;
    float a = 0.f;
    #pragma unroll 8
    for (int s = 0; s < SQ; ++s)
      a += pw[s] * enc[(size_t)s*H + col];
    ws->concat[H + col] = a;
  }
}

// k_b(t): pure FC. 500 blocks x 64 rows, 4 waves; 4 rows/wave/iter x 4 iters
// (32 float4 loads in flight per lane). Then per-block logit partials.
__global__ void __launch_bounds__(NTB) k_b(const float* __restrict__ W_fc,
                                           const float* __restrict__ b_fc,
                                           WS* __restrict__ ws){
  __shared__ float lg[BROWS];
  int b = blockIdx.x, tid = threadIdx.x;
  int wv = tid >> 6, ln = tid & 63;

  // concat slice into registers (same lane->col mapping as before: bit-identical)
  float cv[32];
  {
    const float4* cp = (const float4*)ws->concat + ln;
    #pragma unroll
    for (int k = 0; k < 8; ++k){
      float4 v = cp[k*64];
      cv[k*4+0] = v.x; cv[k*4+1] = v.y; cv[k*4+2] = v.z; cv[k*4+3] = v.w;
    }
  }

  #pragma unroll
  for (int it = 0; it < 4; ++it){
    int l = wv*4 + it*16;                        // 0..63, no clamping needed
    int row = b*BROWS + l;
    const float4* p0 = (const float4*)(W_fc + (size_t)(row+0)*2048) + ln;
    const float4* p1 = (const float4*)(W_fc + (size_t)(row+1)*2048) + ln;
    const float4* p2 = (const float4*)(W_fc + (size_t)(row+2)*2048) + ln;
    const float4* p3 = (const float4*)(W_fc + (size_t)(row+3)*2048) + ln;
    float4 w0[8], w1[8], w2[8], w3[8];
    #pragma unroll
    for (int k = 0; k < 8; ++k) w0[k] = p0[(size_t)k*64];
    #pragma unroll
    for (int k = 0; k < 8; ++k) w1[k] = p1[(size_t)k*64];
    #pragma unroll
    for (int k = 0; k < 8; ++k) w2[k] = p2[(size_t)k*64];
    #pragma unroll
    for (int k = 0; k < 8; ++k) w3[k] = p3[(size_t)k*64];
    float a0 = 0.f, a1 = 0.f, a2 = 0.f, a3 = 0.f;
    #pragma unroll
    for (int k = 0; k < 8; ++k){
      a0 += dot4(w0[k], cv + k*4);
      a1 += dot4(w1[k], cv + k*4);
      a2 += dot4(w2[k], cv + k*4);
      a3 += dot4(w3[k], cv + k*4);
    }
    a0 = wave_sum(a0);
    a1 = wave_sum(a1);
    a2 = wave_sum(a2);
    a3 = wave_sum(a3);
    if (ln == 0){
      float x0 = a0 + b_fc[row+0];
      float x1 = a1 + b_fc[row+1];
      float x2 = a2 + b_fc[row+2];
      float x3 = a3 + b_fc[row+3];
      ws->logits[row+0] = x0; lg[l+0] = x0;
      ws->logits[row+1] = x1; lg[l+1] = x1;
      ws->logits[row+2] = x2; lg[l+2] = x2;
      ws->logits[row+3] = x3; lg[l+3] = x3;
    }
  }
  __syncthreads();

  // block-local max / sumexp / packed argmax key — wave 0 only (64 rows, 1/lane)
  if (wv == 0){
    float v = lg[ln];
    float mb = wave_max(v);
    float sb = wave_sum(expf(v - mb));

    u32 u = __float_as_uint(v);
    u32 srt = (u >> 31) ? ~u : (u | 0x80000000u);   // monotone float->uint map
    u64 key = ((u64)srt << 32) | (u32)(~(u32)(b*BROWS + ln));  // ties -> smaller row
    key = wave_max_u64(key);

    if (ln == 0){
      ws->pmax[b] = mb;
      ws->psum[b] = sb;
      ws->pkey[b] = key;
    }
  }
}

extern "C" void kernel_launch(void* const* d_in, const int* in_sizes, int n_in,
                              void* d_out, int out_size, void* d_ws, size_t ws_size,
                              hipStream_t stream){
  const float* hn   = (const float*)d_in[0];
  const float* cn   = (const float*)d_in[1];
  const float* enc  = (const float*)d_in[2];
  const float* emb  = (const float*)d_in[3];
  const float* W_ih = (const float*)d_in[4];
  const float* W_hh = (const float*)d_in[5];
  const float* b_ih = (const float*)d_in[6];
  const float* b_hh = (const float*)d_in[7];
  const float* W_fc = (const float*)d_in[8];
  const float* b_fc = (const float*)d_in[9];
  float* out = (float*)d_out;
  WS* ws = (WS*)d_ws;
  if (ws_size < sizeof(WS)) return;  // needs ~172 KB

  k_init<<<1, NTI, 0, stream>>>(hn, cn, ws);
  for (int t = 0; t <= T; ++t){
    k_a<<<NB, NTA, 0, stream>>>(emb, W_ih, W_hh, b_ih, b_hh, ws, out, t);
    if (t < T){
      k_c<<<1,   NTC, 0, stream>>>(enc, ws, t);
      k_b<<<NBB, NTB, 0, stream>>>(W_fc, b_fc, ws);
    }
  }
}

// Round 8
// 6942.249 us; speedup vs baseline: 1.0915x; 1.0915x over previous
//
#include <hip/hip_runtime.h>
#include <hip/hip_bf16.h>
#include <math.h>

#define V 32000
#define E 512
#define H 1024
#define SQ 128
#define T 100
#define NB 256      // blocks (both paths)
#define NBLK 256
#define NTI 256
#define NTA 512
#define NTB 512
#define NT 512      // persistent kernel threads
#define GROWS 16    // 4096 gate rows / 256 blocks
#define FROWS 125   // 32000 fc rows / 256 blocks
#define NEG_BIG (-1e30f)

typedef unsigned int u32;
typedef unsigned long long u64;

struct WS {
  float gates[4*H];        // gate pre-activations for current step
  float h[H];              // hidden state (fallback path)
  float c[2][H];           // cell state (fallback path)
  float logits[V];         // raw logits (fallback path)
  float pmax[NB];          // per-block max logit
  float psum[NB];          // per-block sum exp(logit - blockmax)
  u64   pkey[NB];          // per-block packed argmax key
  u32   pad[30];
  u32   bar_cnt;           // grid barrier arrival counter
  u32   bar_gen;           // grid barrier generation
};

__device__ __forceinline__ float wave_sum(float v){
  #pragma unroll
  for (int m = 32; m; m >>= 1) v += __shfl_xor(v, m, 64);
  return v;
}

__device__ __forceinline__ float wave_max(float v){
  #pragma unroll
  for (int m = 32; m; m >>= 1) v = fmaxf(v, __shfl_xor(v, m, 64));
  return v;
}

__device__ __forceinline__ u64 wave_max_u64(u64 v){
  #pragma unroll
  for (int m = 32; m; m >>= 1){
    u64 o = __shfl_xor(v, m, 64);
    v = (o > v) ? o : v;
  }
  return v;
}

__device__ __forceinline__ float dot4(float4 w, const float* v){
  return w.x*v[0] + w.y*v[1] + w.z*v[2] + w.w*v[3];
}

// grid-wide barrier, __ockl_grid_sync pattern: release fence by every thread,
// lane-0 atomic arrive + generation spin, acquire fence by every thread.
__device__ __forceinline__ void gsync(WS* ws){
  __builtin_amdgcn_fence(__ATOMIC_RELEASE, "agent");
  __syncthreads();
  if (threadIdx.x == 0){
    u32 g = __hip_atomic_load(&ws->bar_gen, __ATOMIC_RELAXED, __HIP_MEMORY_SCOPE_AGENT);
    u32 a = __hip_atomic_fetch_add(&ws->bar_cnt, 1u, __ATOMIC_ACQ_REL, __HIP_MEMORY_SCOPE_AGENT);
    if (a == (u32)(NBLK - 1)){
      __hip_atomic_store(&ws->bar_cnt, 0u, __ATOMIC_RELAXED, __HIP_MEMORY_SCOPE_AGENT);
      __hip_atomic_fetch_add(&ws->bar_gen, 1u, __ATOMIC_RELEASE, __HIP_MEMORY_SCOPE_AGENT);
    } else {
      while (__hip_atomic_load(&ws->bar_gen, __ATOMIC_RELAXED, __HIP_MEMORY_SCOPE_AGENT) == g)
        __builtin_amdgcn_s_sleep(8);
    }
  }
  __syncthreads();
  __builtin_amdgcn_fence(__ATOMIC_ACQUIRE, "agent");
}

__global__ void __launch_bounds__(NTI) k_init(const float* __restrict__ hn,
                                              const float* __restrict__ cn,
                                              WS* __restrict__ ws){
  int tid = threadIdx.x;
  for (int j = tid; j < H; j += NTI){
    ws->h[j]    = hn[j];
    ws->c[0][j] = cn[j];
  }
  ws->pmax[tid] = NEG_BIG;
  ws->psum[tid] = 0.f;
  ws->pkey[tid] = 0ull;
  if (tid == 0){ ws->bar_cnt = 0u; ws->bar_gen = 0u; }
}

// ============================ persistent kernel ============================
// 256 blocks x 512 threads, 1 block/CU. Whole decode in one dispatch;
// 2 grid barriers per step replace 2 kernel launches (~6.8 us gap each).
// h/c/concat/logits live in LDS; only gates + partials cross blocks.
__global__ void __launch_bounds__(NT, 2)
k_all(const float* __restrict__ hn, const float* __restrict__ cn,
      const float* __restrict__ enc, const float* __restrict__ emb,
      const float* __restrict__ W_ih, const float* __restrict__ W_hh,
      const float* __restrict__ b_ih, const float* __restrict__ b_hh,
      const float* __restrict__ W_fc, const float* __restrict__ b_fc,
      WS* __restrict__ ws, float* __restrict__ out)
{
  __shared__ float hs[H];          // hidden state h (= h2 after cell)
  __shared__ float cs[H];          // cell state
  __shared__ float cx[H];          // attention context
  __shared__ float sc[SQ];
  __shared__ float pw[SQ];
  __shared__ float lg[FROWS + 3]; // this block's 125 logits
  __shared__ float bc_logZ;
  __shared__ int   bc_tok;

  const int b = blockIdx.x, tid = threadIdx.x;
  const int wv = tid >> 6, ln = tid & 63;

  for (int j = tid; j < H; j += NT){ hs[j] = hn[j]; cs[j] = cn[j]; }
  __syncthreads();

  int tok = 2;  // SOS
  for (int t = 0; t < T; ++t){
    // ---- phase G: gates for this block's 16 rows (reads hs, emb[tok]) ----
    {
      float xv[8], hv[16];
      const float4* xp = (const float4*)(emb + (size_t)tok*E) + ln*2;
      float4 x0 = xp[0], x1 = xp[1];
      xv[0]=x0.x; xv[1]=x0.y; xv[2]=x0.z; xv[3]=x0.w;
      xv[4]=x1.x; xv[5]=x1.y; xv[6]=x1.z; xv[7]=x1.w;
      #pragma unroll
      for (int k = 0; k < 16; ++k) hv[k] = hs[ln*16 + k];

      int row0 = b*GROWS + wv*2, row1 = row0 + 1;
      const float4* ap0 = (const float4*)(W_ih + (size_t)row0*E) + ln*2;
      const float4* ap1 = (const float4*)(W_ih + (size_t)row1*E) + ln*2;
      const float4* wh0 = (const float4*)(W_hh + (size_t)row0*H) + ln*4;
      const float4* wh1 = (const float4*)(W_hh + (size_t)row1*H) + ln*4;
      float4 ia[2], ib[2], ha[4], hb[4];
      #pragma unroll
      for (int k = 0; k < 2; ++k) ia[k] = ap0[k];
      #pragma unroll
      for (int k = 0; k < 2; ++k) ib[k] = ap1[k];
      #pragma unroll
      for (int k = 0; k < 4; ++k) ha[k] = wh0[k];
      #pragma unroll
      for (int k = 0; k < 4; ++k) hb[k] = wh1[k];
      float acc0 = dot4(ia[0], xv) + dot4(ia[1], xv+4)
                 + dot4(ha[0], hv) + dot4(ha[1], hv+4) + dot4(ha[2], hv+8) + dot4(ha[3], hv+12);
      float acc1 = dot4(ib[0], xv) + dot4(ib[1], xv+4)
                 + dot4(hb[0], hv) + dot4(hb[1], hv+4) + dot4(hb[2], hv+8) + dot4(hb[3], hv+12);
      acc0 = wave_sum(acc0);
      acc1 = wave_sum(acc1);
      if (ln == 0){
        ws->gates[row0] = acc0 + b_ih[row0] + b_hh[row0];
        ws->gates[row1] = acc1 + b_ih[row1] + b_hh[row1];
      }
    }
    gsync(ws);   // all 4096 gates visible

    // ---- phase C: LSTM cell (redundant per block; state stays in LDS) ----
    {
      #pragma unroll
      for (int k = 0; k < 2; ++k){
        int j = tid + k*NT;
        float gi = ws->gates[j];
        float gf = ws->gates[H + j];
        float gg = ws->gates[2*H + j];
        float go = ws->gates[3*H + j];
        float co = cs[j];
        float si = 1.f/(1.f + expf(-gi));
        float sf = 1.f/(1.f + expf(-gf));
        float tg = tanhf(gg);
        float so = 1.f/(1.f + expf(-go));
        float cn_ = sf*co + si*tg;
        float hn_ = so*tanhf(cn_);
        cs[j] = cn_;
        hs[j] = hn_;
      }
    }
    __syncthreads();

    // ---- phase A: attention scores = enc @ h2 (8 waves x 16 rows, paired) ----
    {
      float hv[16];
      #pragma unroll
      for (int k = 0; k < 16; ++k) hv[k] = hs[ln*16 + k];
      #pragma unroll
      for (int u = 0; u < 8; ++u){
        int s0 = wv*16 + u*2, s1 = s0 + 1;
        const float4* e0p = (const float4*)(enc + (size_t)s0*H) + ln*4;
        const float4* e1p = (const float4*)(enc + (size_t)s1*H) + ln*4;
        float4 e0[4], e1[4];
        #pragma unroll
        for (int k = 0; k < 4; ++k) e0[k] = e0p[k];
        #pragma unroll
        for (int k = 0; k < 4; ++k) e1[k] = e1p[k];
        float acc0 = dot4(e0[0], hv) + dot4(e0[1], hv+4) + dot4(e0[2], hv+8) + dot4(e0[3], hv+12);
        float acc1 = dot4(e1[0], hv) + dot4(e1[1], hv+4) + dot4(e1[2], hv+8) + dot4(e1[3], hv+12);
        acc0 = wave_sum(acc0);
        acc1 = wave_sum(acc1);
        if (ln == 0){ sc[s0] = acc0; sc[s1] = acc1; }
      }
    }
    __syncthreads();

    // ---- softmax over 128 scores (wave 0) ----
    if (wv == 0){
      float v0 = sc[ln], v1 = sc[ln + 64];
      float m = wave_max(fmaxf(v0, v1));
      float e0 = expf(v0 - m), e1 = expf(v1 - m);
      float S = wave_sum(e0 + e1);
      pw[ln]      = e0 / S;
      pw[ln + 64] = e1 / S;
    }
    __syncthreads();

    // ---- ctx: 512 threads x 2 contiguous cols ----
    {
      float a0 = 0.f, a1 = 0.f;
      const float2* eb = (const float2*)enc + tid;
      #pragma unroll 8
      for (int s = 0; s < SQ; ++s){
        float2 e = eb[(size_t)s*(H/2)];
        float w = pw[s];
        a0 += w*e.x; a1 += w*e.y;
      }
      cx[tid*2 + 0] = a0;
      cx[tid*2 + 1] = a1;
    }
    __syncthreads();

    // ---- phase F: FC, this block's 125 rows; logits into LDS only ----
    {
      float cv[32];
      #pragma unroll
      for (int k = 0; k < 4; ++k)
        #pragma unroll
        for (int m = 0; m < 4; ++m)
          cv[k*4 + m] = hs[k*256 + ln*4 + m];
      #pragma unroll
      for (int k = 0; k < 4; ++k)
        #pragma unroll
        for (int m = 0; m < 4; ++m)
          cv[16 + k*4 + m] = cx[k*256 + ln*4 + m];

      #pragma unroll
      for (int it = 0; it < 4; ++it){
        int l = wv*4 + it*32;
        int c1 = l+1, c2 = l+2, c3 = l+3;
        if (c1 > FROWS-1) c1 = FROWS-1;
        if (c2 > FROWS-1) c2 = FROWS-1;
        if (c3 > FROWS-1) c3 = FROWS-1;
        const float4* p0 = (const float4*)(W_fc + (size_t)(b*FROWS + l )*2048) + ln;
        const float4* p1 = (const float4*)(W_fc + (size_t)(b*FROWS + c1)*2048) + ln;
        const float4* p2 = (const float4*)(W_fc + (size_t)(b*FROWS + c2)*2048) + ln;
        const float4* p3 = (const float4*)(W_fc + (size_t)(b*FROWS + c3)*2048) + ln;
        float4 w0[8], w1[8], w2[8], w3[8];
        #pragma unroll
        for (int k = 0; k < 8; ++k) w0[k] = p0[(size_t)k*64];
        #pragma unroll
        for (int k = 0; k < 8; ++k) w1[k] = p1[(size_t)k*64];
        #pragma unroll
        for (int k = 0; k < 8; ++k) w2[k] = p2[(size_t)k*64];
        #pragma unroll
        for (int k = 0; k < 8; ++k) w3[k] = p3[(size_t)k*64];
        float a0 = 0.f, a1 = 0.f, a2 = 0.f, a3 = 0.f;
        #pragma unroll
        for (int k = 0; k < 8; ++k){
          a0 += dot4(w0[k], cv + k*4);
          a1 += dot4(w1[k], cv + k*4);
          a2 += dot4(w2[k], cv + k*4);
          a3 += dot4(w3[k], cv + k*4);
        }
        a0 = wave_sum(a0);
        a1 = wave_sum(a1);
        a2 = wave_sum(a2);
        a3 = wave_sum(a3);
        if (ln == 0){
          int row = b*FROWS + l;
          {                 lg[l]   = a0 + b_fc[row];   }
          if (l+1 < FROWS){ lg[l+1] = a1 + b_fc[row+1]; }
          if (l+2 < FROWS){ lg[l+2] = a2 + b_fc[row+2]; }
          if (l+3 < FROWS){ lg[l+3] = a3 + b_fc[row+3]; }
        }
      }
    }
    __syncthreads();

    // ---- block partials (wave 0) ----
    if (wv == 0){
      float v0 = (ln < FROWS)      ? lg[ln]      : NEG_BIG;
      float v1 = (ln + 64 < FROWS) ? lg[ln + 64] : NEG_BIG;
      float mb = wave_max(fmaxf(v0, v1));
      float e  = expf(v0 - mb) + expf(v1 - mb);
      float sb = wave_sum(e);

      u64 k0 = 0ull, k1 = 0ull;
      if (ln < FROWS){
        u32 u = __float_as_uint(v0);
        u32 srt = (u >> 31) ? ~u : (u | 0x80000000u);
        k0 = ((u64)srt << 32) | (u32)(~(u32)(b*FROWS + ln));
      }
      if (ln + 64 < FROWS){
        u32 u = __float_as_uint(v1);
        u32 srt = (u >> 31) ? ~u : (u | 0x80000000u);
        k1 = ((u64)srt << 32) | (u32)(~(u32)(b*FROWS + ln + 64));
      }
      u64 key = wave_max_u64((k0 > k1) ? k0 : k1);
      if (ln == 0){
        ws->pmax[b] = mb;
        ws->psum[b] = sb;
        ws->pkey[b] = key;
      }
    }
    gsync(ws);   // all 256 partials visible

    // ---- finalize (redundant per block, wave 0): logZ + argmax token ----
    if (wv == 0){
      float mb0 = ws->pmax[ln],       mb1 = ws->pmax[ln+64];
      float mb2 = ws->pmax[ln+128],   mb3 = ws->pmax[ln+192];
      float sb0 = ws->psum[ln],       sb1 = ws->psum[ln+64];
      float sb2 = ws->psum[ln+128],   sb3 = ws->psum[ln+192];
      u64   kb0 = ws->pkey[ln],       kb1 = ws->pkey[ln+64];
      u64   kb2 = ws->pkey[ln+128],   kb3 = ws->pkey[ln+192];
      float m = wave_max(fmaxf(fmaxf(mb0, mb1), fmaxf(mb2, mb3)));
      float S = sb0*expf(mb0 - m) + sb1*expf(mb1 - m)
              + sb2*expf(mb2 - m) + sb3*expf(mb3 - m);
      S = wave_sum(S);
      u64 ka = (kb0 > kb1) ? kb0 : kb1;
      u64 kc = (kb2 > kb3) ? kb2 : kb3;
      u64 key = wave_max_u64((ka > kc) ? ka : kc);
      if (ln == 0){
        bc_logZ = m + logf(fmaxf(S, 1e-30f));
        int tk = (int)(~(u32)key);
        if ((u32)tk >= (u32)V) tk = 2;
        bc_tok = tk;
      }
    }
    __syncthreads();
    float logZ = bc_logZ;
    tok = bc_tok;

    // ---- write this block's 125 logp rows + index ----
    for (int l = tid; l < FROWS; l += NT)
      __builtin_nontemporal_store(lg[l] - logZ, &out[(size_t)t*V + b*FROWS + l]);
    if (b == 0 && tid == 0)
      out[(size_t)T*V + t] = (float)tok;
    // lg reused only after next FC (post-gsync); hs overwritten after next gsync. Safe.
  }
}

// ============================ fallback path (Round-3, proven) ============================

__global__ void __launch_bounds__(NTA) k_a(const float* __restrict__ emb,
                                           const float* __restrict__ W_ih,
                                           const float* __restrict__ W_hh,
                                           const float* __restrict__ b_ih,
                                           const float* __restrict__ b_hh,
                                           WS* __restrict__ ws,
                                           float* __restrict__ out,
                                           int t){
  __shared__ float bc_logZ;
  __shared__ int   bc_tok;
  int b = blockIdx.x, tid = threadIdx.x;
  int wv = tid >> 6, ln = tid & 63;
  int tok = 2;

  if (t > 0){
    if (wv == 0){
      float mb0 = ws->pmax[ln],       mb1 = ws->pmax[ln+64];
      float mb2 = ws->pmax[ln+128],   mb3 = ws->pmax[ln+192];
      float sb0 = ws->psum[ln],       sb1 = ws->psum[ln+64];
      float sb2 = ws->psum[ln+128],   sb3 = ws->psum[ln+192];
      u64   kb0 = ws->pkey[ln],       kb1 = ws->pkey[ln+64];
      u64   kb2 = ws->pkey[ln+128],   kb3 = ws->pkey[ln+192];
      float m = wave_max(fmaxf(fmaxf(mb0, mb1), fmaxf(mb2, mb3)));
      float S = sb0*expf(mb0 - m) + sb1*expf(mb1 - m)
              + sb2*expf(mb2 - m) + sb3*expf(mb3 - m);
      S = wave_sum(S);
      u64 ka = (kb0 > kb1) ? kb0 : kb1;
      u64 kc = (kb2 > kb3) ? kb2 : kb3;
      u64 key = wave_max_u64((ka > kc) ? ka : kc);
      if (ln == 0){
        bc_logZ = m + logf(fmaxf(S, 1e-30f));
        int tk = (int)(~(u32)key);
        if ((u32)tk >= (u32)V) tk = 2;
        bc_tok = tk;
      }
    }
    __syncthreads();
    float logZ = bc_logZ;
    tok = bc_tok;

    if (tid < FROWS){
      int row = b*FROWS + tid;
      __builtin_nontemporal_store(ws->logits[row] - logZ,
                                  &out[(size_t)(t-1)*V + row]);
    }
    if (b == 0 && tid == 0)
      out[(size_t)T*V + (t-1)] = (float)tok;
  }

  if (t < T){
    float xv[8], hv[16];
    {
      const float4* xp = (const float4*)(emb + (size_t)tok*E) + ln*2;
      float4 x0 = xp[0], x1 = xp[1];
      xv[0]=x0.x; xv[1]=x0.y; xv[2]=x0.z; xv[3]=x0.w;
      xv[4]=x1.x; xv[5]=x1.y; xv[6]=x1.z; xv[7]=x1.w;
      const float4* hp = (const float4*)(ws->h) + ln*4;
      float4 h0 = hp[0], h1 = hp[1], h2 = hp[2], h3 = hp[3];
      hv[0]=h0.x; hv[1]=h0.y; hv[2]=h0.z; hv[3]=h0.w;
      hv[4]=h1.x; hv[5]=h1.y; hv[6]=h1.z; hv[7]=h1.w;
      hv[8]=h2.x; hv[9]=h2.y; hv[10]=h2.z; hv[11]=h2.w;
      hv[12]=h3.x; hv[13]=h3.y; hv[14]=h3.z; hv[15]=h3.w;
    }
    int row0 = b*GROWS + wv*2, row1 = row0 + 1;
    const float4* ap0 = (const float4*)(W_ih + (size_t)row0*E) + ln*2;
    const float4* ap1 = (const float4*)(W_ih + (size_t)row1*E) + ln*2;
    const float4* wh0 = (const float4*)(W_hh + (size_t)row0*H) + ln*4;
    const float4* wh1 = (const float4*)(W_hh + (size_t)row1*H) + ln*4;
    float4 ia[2], ib[2], ha[4], hb[4];
    #pragma unroll
    for (int k = 0; k < 2; ++k) ia[k] = ap0[k];
    #pragma unroll
    for (int k = 0; k < 2; ++k) ib[k] = ap1[k];
    #pragma unroll
    for (int k = 0; k < 4; ++k) ha[k] = wh0[k];
    #pragma unroll
    for (int k = 0; k < 4; ++k) hb[k] = wh1[k];
    float acc0 = dot4(ia[0], xv) + dot4(ia[1], xv+4)
               + dot4(ha[0], hv) + dot4(ha[1], hv+4) + dot4(ha[2], hv+8) + dot4(ha[3], hv+12);
    float acc1 = dot4(ib[0], xv) + dot4(ib[1], xv+4)
               + dot4(hb[0], hv) + dot4(hb[1], hv+4) + dot4(hb[2], hv+8) + dot4(hb[3], hv+12);
    acc0 = wave_sum(acc0);
    acc1 = wave_sum(acc1);
    if (ln == 0){
      ws->gates[row0] = acc0 + b_ih[row0] + b_hh[row0];
      ws->gates[row1] = acc1 + b_ih[row1] + b_hh[row1];
    }
  }
}

__global__ void __launch_bounds__(NTB) k_b(const float* __restrict__ enc,
                                           const float* __restrict__ W_fc,
                                           const float* __restrict__ b_fc,
                                           WS* __restrict__ ws,
                                           int t){
  __shared__ float concat[2*H];
  __shared__ float sc[SQ];
  __shared__ float pw[SQ];
  __shared__ float lg[128];
  int b = blockIdx.x, tid = threadIdx.x;
  int wv = tid >> 6, ln = tid & 63;

  {
    float c2v[2], h2v[2];
    #pragma unroll
    for (int k = 0; k < 2; ++k){
      int j = tid + k*NTB;
      float gi = ws->gates[j];
      float gf = ws->gates[H + j];
      float gg = ws->gates[2*H + j];
      float go = ws->gates[3*H + j];
      float co = ws->c[t & 1][j];
      float si = 1.f/(1.f + expf(-gi));
      float sf = 1.f/(1.f + expf(-gf));
      float tg = tanhf(gg);
      float so = 1.f/(1.f + expf(-go));
      float cn = sf*co + si*tg;
      float hn = so*tanhf(cn);
      c2v[k] = cn; h2v[k] = hn;
      concat[j] = hn;
    }
    if (b == 0){
      #pragma unroll
      for (int k = 0; k < 2; ++k){
        int j = tid + k*NTB;
        ws->c[(t+1) & 1][j] = c2v[k];
        ws->h[j] = h2v[k];
      }
    }
  }
  __syncthreads();

  {
    float hv[16];
    #pragma unroll
    for (int k = 0; k < 16; ++k) hv[k] = concat[ln*16 + k];
    #pragma unroll
    for (int u = 0; u < 8; ++u){
      int s0 = wv*16 + u*2, s1 = s0 + 1;
      const float4* e0p = (const float4*)(enc + (size_t)s0*H) + ln*4;
      const float4* e1p = (const float4*)(enc + (size_t)s1*H) + ln*4;
      float4 e0[4], e1[4];
      #pragma unroll
      for (int k = 0; k < 4; ++k) e0[k] = e0p[k];
      #pragma unroll
      for (int k = 0; k < 4; ++k) e1[k] = e1p[k];
      float acc0 = dot4(e0[0], hv) + dot4(e0[1], hv+4) + dot4(e0[2], hv+8) + dot4(e0[3], hv+12);
      float acc1 = dot4(e1[0], hv) + dot4(e1[1], hv+4) + dot4(e1[2], hv+8) + dot4(e1[3], hv+12);
      acc0 = wave_sum(acc0);
      acc1 = wave_sum(acc1);
      if (ln == 0){ sc[s0] = acc0; sc[s1] = acc1; }
    }
  }
  __syncthreads();

  if (wv == 0){
    float v0 = sc[ln], v1 = sc[ln + 64];
    float m = wave_max(fmaxf(v0, v1));
    float e0 = expf(v0 - m), e1 = expf(v1 - m);
    float S = wave_sum(e0 + e1);
    pw[ln]      = e0 / S;
    pw[ln + 64] = e1 / S;
  }
  __syncthreads();

  {
    float a0 = 0.f, a1 = 0.f;
    const float2* eb = (const float2*)enc + tid;
    #pragma unroll 8
    for (int s = 0; s < SQ; ++s){
      float2 e = eb[(size_t)s*(H/2)];
      float w = pw[s];
      a0 += w*e.x; a1 += w*e.y;
    }
    concat[H + tid*2 + 0] = a0;
    concat[H + tid*2 + 1] = a1;
  }
  __syncthreads();

  {
    float cv[32];
    #pragma unroll
    for (int k = 0; k < 8; ++k)
      #pragma unroll
      for (int m = 0; m < 4; ++m)
        cv[k*4 + m] = concat[k*256 + ln*4 + m];

    #pragma unroll
    for (int it = 0; it < 4; ++it){
      int l = wv*4 + it*32;
      int c1 = l+1, c2 = l+2, c3 = l+3;
      if (c1 > FROWS-1) c1 = FROWS-1;
      if (c2 > FROWS-1) c2 = FROWS-1;
      if (c3 > FROWS-1) c3 = FROWS-1;
      const float4* p0 = (const float4*)(W_fc + (size_t)(b*FROWS + l )*2048) + ln;
      const float4* p1 = (const float4*)(W_fc + (size_t)(b*FROWS + c1)*2048) + ln;
      const float4* p2 = (const float4*)(W_fc + (size_t)(b*FROWS + c2)*2048) + ln;
      const float4* p3 = (const float4*)(W_fc + (size_t)(b*FROWS + c3)*2048) + ln;
      float4 w0[8], w1[8], w2[8], w3[8];
      #pragma unroll
      for (int k = 0; k < 8; ++k) w0[k] = p0[(size_t)k*64];
      #pragma unroll
      for (int k = 0; k < 8; ++k) w1[k] = p1[(size_t)k*64];
      #pragma unroll
      for (int k = 0; k < 8; ++k) w2[k] = p2[(size_t)k*64];
      #pragma unroll
      for (int k = 0; k < 8; ++k) w3[k] = p3[(size_t)k*64];
      float a0 = 0.f, a1 = 0.f, a2 = 0.f, a3 = 0.f;
      #pragma unroll
      for (int k = 0; k < 8; ++k){
        a0 += dot4(w0[k], cv + k*4);
        a1 += dot4(w1[k], cv + k*4);
        a2 += dot4(w2[k], cv + k*4);
        a3 += dot4(w3[k], cv + k*4);
      }
      a0 = wave_sum(a0);
      a1 = wave_sum(a1);
      a2 = wave_sum(a2);
      a3 = wave_sum(a3);
      if (ln == 0){
        int row = b*FROWS + l;
        {                 float x = a0 + b_fc[row];   ws->logits[row]   = x; lg[l]   = x; }
        if (l+1 < FROWS){ float x = a1 + b_fc[row+1]; ws->logits[row+1] = x; lg[l+1] = x; }
        if (l+2 < FROWS){ float x = a2 + b_fc[row+2]; ws->logits[row+2] = x; lg[l+2] = x; }
        if (l+3 < FROWS){ float x = a3 + b_fc[row+3]; ws->logits[row+3] = x; lg[l+3] = x; }
      }
    }
  }
  __syncthreads();

  if (wv == 0){
    float v0 = (ln < FROWS)      ? lg[ln]      : NEG_BIG;
    float v1 = (ln + 64 < FROWS) ? lg[ln + 64] : NEG_BIG;
    float mb = wave_max(fmaxf(v0, v1));
    float e  = expf(v0 - mb) + expf(v1 - mb);
    float sb = wave_sum(e);

    u64 k0 = 0ull, k1 = 0ull;
    if (ln < FROWS){
      u32 u = __float_as_uint(v0);
      u32 srt = (u >> 31) ? ~u : (u | 0x80000000u);
      k0 = ((u64)srt << 32) | (u32)(~(u32)(b*FROWS + ln));
    }
    if (ln + 64 < FROWS){
      u32 u = __float_as_uint(v1);
      u32 srt = (u >> 31) ? ~u : (u | 0x80000000u);
      k1 = ((u64)srt << 32) | (u32)(~(u32)(b*FROWS + ln + 64));
    }
    u64 key = wave_max_u64((k0 > k1) ? k0 : k1);

    if (ln == 0){
      ws->pmax[b] = mb;
      ws->psum[b] = sb;
      ws->pkey[b] = key;
    }
  }
}

extern "C" void kernel_launch(void* const* d_in, const int* in_sizes, int n_in,
                              void* d_out, int out_size, void* d_ws, size_t ws_size,
                              hipStream_t stream){
  const float* hn   = (const float*)d_in[0];
  const float* cn   = (const float*)d_in[1];
  const float* enc  = (const float*)d_in[2];
  const float* emb  = (const float*)d_in[3];
  const float* W_ih = (const float*)d_in[4];
  const float* W_hh = (const float*)d_in[5];
  const float* b_ih = (const float*)d_in[6];
  const float* b_hh = (const float*)d_in[7];
  const float* W_fc = (const float*)d_in[8];
  const float* b_fc = (const float*)d_in[9];
  float* out = (float*)d_out;
  WS* ws = (WS*)d_ws;
  if (ws_size < sizeof(WS)) return;

  k_init<<<1, NTI, 0, stream>>>(hn, cn, ws);

  int maxb = 0;
  hipError_t err = hipOccupancyMaxActiveBlocksPerMultiprocessor(
      &maxb, reinterpret_cast<const void*>(k_all), NT, 0);
  if (err == hipSuccess && maxb >= 1){
    // persistent path: 256 blocks x 512 threads, co-resident (1 block/CU)
    k_all<<<NBLK, NT, 0, stream>>>(hn, cn, enc, emb, W_ih, W_hh,
                                   b_ih, b_hh, W_fc, b_fc, ws, out);
  } else {
    // proven Round-3 two-kernel path
    for (int t = 0; t <= T; ++t){
      k_a<<<NB, NTA, 0, stream>>>(emb, W_ih, W_hh, b_ih, b_hh, ws, out, t);
      if (t < T) k_b<<<NB, NTB, 0, stream>>>(enc, W_fc, b_fc, ws, t);
    }
  }
}